// Round 19
// baseline (41.707 us; speedup 1.0000x reference)
//
#include <hip/hip_runtime.h>

#define T_DIM 1024

typedef short short8 __attribute__((ext_vector_type(8)));
typedef float f32x4  __attribute__((ext_vector_type(4)));

__device__ __forceinline__ unsigned pk_bf16(float lo, float hi) {
    unsigned r;
    asm("v_cvt_pk_bf16_f32 %0, %1, %2" : "=v"(r) : "v"(lo), "v"(hi));
    return r;
}

// Single-instruction DPP allreduces over 16-lane rows (R10, verified).
__device__ __forceinline__ float allred_add16_s(float v) {
    asm volatile(
        "s_nop 1\n\t"
        "v_add_f32_dpp %0,%0,%0 row_ror:8 row_mask:0xf bank_mask:0xf\n\t"
        "s_nop 1\n\t"
        "v_add_f32_dpp %0,%0,%0 row_ror:4 row_mask:0xf bank_mask:0xf\n\t"
        "s_nop 1\n\t"
        "v_add_f32_dpp %0,%0,%0 row_ror:2 row_mask:0xf bank_mask:0xf\n\t"
        "s_nop 1\n\t"
        "v_add_f32_dpp %0,%0,%0 row_ror:1 row_mask:0xf bank_mask:0xf"
        : "+v"(v));
    return v;
}
__device__ __forceinline__ void allred_add16_x4(float& a, float& b, float& c, float& d) {
    asm volatile(
        "s_nop 1\n\t"
        "v_add_f32_dpp %0,%0,%0 row_ror:8 row_mask:0xf bank_mask:0xf\n\t"
        "v_add_f32_dpp %1,%1,%1 row_ror:8 row_mask:0xf bank_mask:0xf\n\t"
        "v_add_f32_dpp %2,%2,%2 row_ror:8 row_mask:0xf bank_mask:0xf\n\t"
        "v_add_f32_dpp %3,%3,%3 row_ror:8 row_mask:0xf bank_mask:0xf\n\t"
        "v_add_f32_dpp %0,%0,%0 row_ror:4 row_mask:0xf bank_mask:0xf\n\t"
        "v_add_f32_dpp %1,%1,%1 row_ror:4 row_mask:0xf bank_mask:0xf\n\t"
        "v_add_f32_dpp %2,%2,%2 row_ror:4 row_mask:0xf bank_mask:0xf\n\t"
        "v_add_f32_dpp %3,%3,%3 row_ror:4 row_mask:0xf bank_mask:0xf\n\t"
        "v_add_f32_dpp %0,%0,%0 row_ror:2 row_mask:0xf bank_mask:0xf\n\t"
        "v_add_f32_dpp %1,%1,%1 row_ror:2 row_mask:0xf bank_mask:0xf\n\t"
        "v_add_f32_dpp %2,%2,%2 row_ror:2 row_mask:0xf bank_mask:0xf\n\t"
        "v_add_f32_dpp %3,%3,%3 row_ror:2 row_mask:0xf bank_mask:0xf\n\t"
        "v_add_f32_dpp %0,%0,%0 row_ror:1 row_mask:0xf bank_mask:0xf\n\t"
        "v_add_f32_dpp %1,%1,%1 row_ror:1 row_mask:0xf bank_mask:0xf\n\t"
        "v_add_f32_dpp %2,%2,%2 row_ror:1 row_mask:0xf bank_mask:0xf\n\t"
        "v_add_f32_dpp %3,%3,%3 row_ror:1 row_mask:0xf bank_mask:0xf"
        : "+v"(a), "+v"(b), "+v"(c), "+v"(d));
}

__device__ __forceinline__ void wave_ds_fence() {
    asm volatile("s_waitcnt lgkmcnt(0)" ::: "memory");
}

template <int CODE>
__device__ __forceinline__ float swz_xor(float v) {
    return __int_as_float(__builtin_amdgcn_ds_swizzle(__float_as_int(v), CODE));
}

// bf16 U layout (R7/R16, measured 0 bank conflicts): short index
// = q*256 + ((((o>>2)^(q&15))<<2) | (o&3)); b64 writes/reads conflict-free.
// Wave w's writes/reads stay within shorts q*256 + [w*64, w*64+64) -- this
// 4 KB stripe-set is wave w's PRIVATE footprint (epilogue + phase 2).
__device__ __forceinline__ int sidx(int q, int o) {
    return q * 256 + ((((o >> 2) ^ (q & 15)) << 2) | (o & 3));
}
__device__ __forceinline__ float bf_lo(unsigned u) { return __uint_as_float(u << 16); }
__device__ __forceinline__ float bf_hi(unsigned u) { return __uint_as_float(u & 0xffff0000u); }

// One block per (b,t), 4 waves, zero barriers, 16 KB LDS -> 8 blocks/CU.
// R16 body + kpack folded in WITHOUT a prologue kernel. K staging lives in
// wave w's OWN epilogue footprint (u32 idx = (col>>1)*128 + w*32 +
// (col&1)*16 + m), so staging -> af-read -> U-overwrite -> phase-2 are all
// wave-private and per-wave in-order DS + lgkmcnt fences suffice (the R18
// NaN was cross-wave clobber from quarter-based staging).
__global__ __launch_bounds__(256, 8) void caps_kernel(
    const float* __restrict__ x,     // (B,T,32,8)
    const float* __restrict__ Bw,    // (T,16,1,32)
    const float* __restrict__ K,     // (3,8,256)
    const float* __restrict__ bias,  // (256)
    float* __restrict__ out)         // (B,T,16,16)
{
    const int bt  = blockIdx.x;
    const int t   = bt & (T_DIM - 1);
    const int tid = threadIdx.x;
    const int l   = tid & 63;
    const int w   = tid >> 6;
    const int kb  = l >> 4;
    const int r16 = l & 15;
    const int n   = tid >> 4, j = tid & 15;

    __shared__ unsigned short U16[32 * 256];   // U tile; doubles as K staging

    // ---- Bw prefetch ----
    const float bwj0 = Bw[(size_t)t * 512 + n * 32 + j];
    const float bwj1 = Bw[(size_t)t * 512 + n * 32 + 16 + j];

    // ---- B fragments: X^T columns (kt == kb); kb==3 = bias partner 1.0 ----
    short8 bx[2];
    if (kb == 3) {
        union { short8 s; uint4 u; } one;
        one.u = make_uint4(0x00003F80u, 0u, 0u, 0u);   // bf16(1.0) at e0
        bx[0] = bx[1] = one.s;
    } else {
        const int  tt    = t + kb - 1;
        const bool valid = (tt >= 0) && (tt < T_DIM);
        #pragma unroll
        for (int qt = 0; qt < 2; ++qt) {
            float4 x0 = make_float4(0.f, 0.f, 0.f, 0.f), x1 = x0;
            if (valid) {
                const float* xp = x + ((size_t)(bt + kb - 1) * 256 + (qt * 16 + r16) * 8);
                x0 = *reinterpret_cast<const float4*>(xp);
                x1 = *reinterpret_cast<const float4*>(xp + 4);
            }
            union { short8 s; uint4 u; } bu;
            bu.u.x = pk_bf16(x0.x, x0.y);
            bu.u.y = pk_bf16(x0.z, x0.w);
            bu.u.z = pk_bf16(x1.x, x1.y);
            bu.u.w = pk_bf16(x1.z, x1.w);
            bx[qt] = bu.s;
        }
    }

    // ---- stage this wave's K slice into its OWN footprint ----
    // (col in [0,64), m in [0,16)) -> u32 idx (col>>1)*128 + w*32 +
    // (col&1)*16 + m. Word m = bf16 pair (K[2m][w*64+col], K[2m+1][..])
    // for m<12; words 12..15 = (bias,0),0,0,0.
    unsigned* Kl = reinterpret_cast<unsigned*>(U16);
    #define KLIDX(col, m) ((((col) >> 1) << 7) + (w << 5) + (((col) & 1) << 4) + (m))
    #pragma unroll
    for (int it = 0; it < 3; ++it) {
        const int task = it * 64 + l;
        const int p = task >> 4;          // row pair 0..11
        const int g = task & 15;          // col group (4 cols)
        const float* kp0 = K + (2 * p) * 256 + w * 64 + g * 4;
        const float4 ra = *reinterpret_cast<const float4*>(kp0);
        const float4 rb = *reinterpret_cast<const float4*>(kp0 + 256);
        Kl[KLIDX(g * 4 + 0, p)] = pk_bf16(ra.x, rb.x);
        Kl[KLIDX(g * 4 + 1, p)] = pk_bf16(ra.y, rb.y);
        Kl[KLIDX(g * 4 + 2, p)] = pk_bf16(ra.z, rb.z);
        Kl[KLIDX(g * 4 + 3, p)] = pk_bf16(ra.w, rb.w);
    }
    {
        const float bv = bias[w * 64 + l];
        *reinterpret_cast<uint4*>(&Kl[KLIDX(l, 12)]) =
            make_uint4(pk_bf16(bv, 0.f), 0u, 0u, 0u);
    }

    wave_ds_fence();   // staging visible to this wave's own reads

    // ---- A fragments: b128 reads from the staged slice ----
    short8 af[4];
    #pragma unroll
    for (int oti = 0; oti < 4; ++oti) {
        union { short8 s; uint4 u; } au;
        au.u = *reinterpret_cast<const uint4*>(&Kl[KLIDX(oti * 16 + r16, kb * 4)]);
        af[oti] = au.s;
    }
    #undef KLIDX

    // ---- conv MFMAs (af consumed; epilogue may then overwrite staging) ----
    const f32x4 z = (f32x4){0.f, 0.f, 0.f, 0.f};
    f32x4 acc[2][4];
    #pragma unroll
    for (int qt = 0; qt < 2; ++qt)
        #pragma unroll
        for (int oti = 0; oti < 4; ++oti)
            acc[qt][oti] = __builtin_amdgcn_mfma_f32_16x16x32_bf16(
                af[oti], bx[qt], z, 0, 0, 0);

    wave_ds_fence();   // af reads drained before U overwrites (same wave)

    // ---- epilogue: relu -> bf16 -> swizzled b64 writes ----
    #pragma unroll
    for (int qt = 0; qt < 2; ++qt) {
        const int q = qt * 16 + r16;
        #pragma unroll
        for (int oti = 0; oti < 4; ++oti) {
            const int obase = w * 64 + oti * 16 + kb * 4;
            uint2 pk;
            pk.x = pk_bf16(fmaxf(acc[qt][oti][0], 0.f), fmaxf(acc[qt][oti][1], 0.f));
            pk.y = pk_bf16(fmaxf(acc[qt][oti][2], 0.f), fmaxf(acc[qt][oti][3], 0.f));
            *reinterpret_cast<uint2*>(&U16[sidx(q, obase)]) = pk;
        }
    }

    wave_ds_fence();   // all phase-2 reads touch only this wave's columns

    // ---- phase 2: thread = (head n, lane j) ----
    f32x4 r0[4], r1[4];
    #pragma unroll
    for (int i = 0; i < 4; ++i) {
        const uint2 a = *reinterpret_cast<const uint2*>(&U16[sidx(j,      n * 16 + 4 * i)]);
        const uint2 c = *reinterpret_cast<const uint2*>(&U16[sidx(j + 16, n * 16 + 4 * i)]);
        r0[i] = (f32x4){bf_lo(a.x), bf_hi(a.x), bf_lo(a.y), bf_hi(a.y)};
        r1[i] = (f32x4){bf_lo(c.x), bf_hi(c.x), bf_lo(c.y), bf_hi(c.y)};
    }

    // V[d] = sum_q U[q][d] (DPP allreduce over 16 lanes)
    f32x4 V[4];
    #pragma unroll
    for (int i = 0; i < 4; ++i) {
        V[i] = r0[i] + r1[i];
        float a = V[i][0], b = V[i][1], c = V[i][2], d = V[i][3];
        allred_add16_x4(a, b, c, d);
        V[i] = (f32x4){a, b, c, d};
    }

    // scores (unscaled dots)
    float s0 = 0.f, s1 = 0.f;
    #pragma unroll
    for (int i = 0; i < 4; ++i)
        #pragma unroll
        for (int c = 0; c < 4; ++c) {
            s0 = fmaf(V[i][c], r0[i][c], s0);
            s1 = fmaf(V[i][c], r1[i][c], s1);
        }

    // softmax over 32 q: exp(s/sqrt8) = exp2(s*C2); no max-sub (data-bounded)
    const float C2 = 0.51011597846f;   // (1/sqrt(8)) * log2(e)
    const float e0 = exp2f(s0 * C2), e1 = exp2f(s1 * C2);
    const float es = allred_add16_s(e0 + e1);
    const float inv = __builtin_amdgcn_rcpf(es);
    const float c0 = fmaf(e0, inv, bwj0);
    const float c1 = fmaf(e1, inv, bwj1);

    // per-lane partials for all 16 output components
    float op16[16];
    #pragma unroll
    for (int i = 0; i < 4; ++i)
        #pragma unroll
        for (int c = 0; c < 4; ++c)
            op16[4 * i + c] = fmaf(c0, r0[i][c], c1 * r1[i][c]);

    // butterfly reduce-scatter over the 16-lane group: lane j -> out[j]
    float v8[8];
    #pragma unroll
    for (int s = 0; s < 8; ++s) {
        const float kp = (j & 8) ? op16[s + 8] : op16[s];
        const float sd = (j & 8) ? op16[s] : op16[s + 8];
        v8[s] = kp + swz_xor<0x201F>(sd);
    }
    float v4[4];
    #pragma unroll
    for (int s = 0; s < 4; ++s) {
        const float kp = (j & 4) ? v8[s + 4] : v8[s];
        const float sd = (j & 4) ? v8[s] : v8[s + 4];
        v4[s] = kp + swz_xor<0x101F>(sd);
    }
    float v2[2];
    #pragma unroll
    for (int s = 0; s < 2; ++s) {
        const float kp = (j & 2) ? v4[s + 2] : v4[s];
        const float sd = (j & 2) ? v4[s] : v4[s + 2];
        v2[s] = kp + swz_xor<0x081F>(sd);
    }
    const float kp1 = (j & 1) ? v2[1] : v2[0];
    const float sd1 = (j & 1) ? v2[0] : v2[1];
    const float ox = kp1 + swz_xor<0x041F>(sd1);

    // norm gate: ss = sum_d out[d]^2 via scalar allreduce
    const float ss  = allred_add16_s(ox * ox);
    const float nrm = sqrtf(ss);
    const float res = ss * __builtin_amdgcn_rcpf(ss + 1.f) *
                      (ox * __builtin_amdgcn_rcpf(nrm + 1e-7f));

    out[(size_t)bt * 256 + tid] = res;
}

extern "C" void kernel_launch(void* const* d_in, const int* in_sizes, int n_in,
                              void* d_out, int out_size, void* d_ws, size_t ws_size,
                              hipStream_t stream) {
    const float* x    = (const float*)d_in[0];
    const float* K    = (const float*)d_in[1];
    const float* bias = (const float*)d_in[2];
    const float* Bw   = (const float*)d_in[3];
    float* out        = (float*)d_out;

    const int B  = in_sizes[0] / (T_DIM * 32 * 8);   // = 8
    const int nb = B * T_DIM;                        // 8192 blocks
    caps_kernel<<<nb, 256, 0, stream>>>(x, Bw, K, bias, out);
}

// Round 21
// 32.579 us; speedup vs baseline: 1.2802x; 1.2802x over previous
//
#include <hip/hip_runtime.h>

#define T_DIM 1024

typedef short short8 __attribute__((ext_vector_type(8)));
typedef float f32x4  __attribute__((ext_vector_type(4)));

__device__ __forceinline__ unsigned pk_bf16(float lo, float hi) {
    unsigned r;
    asm("v_cvt_pk_bf16_f32 %0, %1, %2" : "=v"(r) : "v"(lo), "v"(hi));
    return r;
}

// Pack K (3,8,256) f32 -> bf16 fragments; k-row 24 (kb==3,e==0) carries bias.
__global__ void kpack_kernel(const float* __restrict__ K,
                             const float* __restrict__ bias,
                             uint4* __restrict__ Kp) {
    const int kb  = blockIdx.x;
    const int col = threadIdx.x;
    uint4 wv = make_uint4(0u, 0u, 0u, 0u);
    if (kb < 3) {
        const float* kp = K + kb * 8 * 256 + col;
        wv.x = pk_bf16(kp[0 * 256], kp[1 * 256]);
        wv.y = pk_bf16(kp[2 * 256], kp[3 * 256]);
        wv.z = pk_bf16(kp[4 * 256], kp[5 * 256]);
        wv.w = pk_bf16(kp[6 * 256], kp[7 * 256]);
    } else {
        wv.x = pk_bf16(bias[col], 0.f);
    }
    Kp[kb * 256 + col] = wv;
}

// Single-instruction DPP allreduces over 16-lane rows (R10, verified).
__device__ __forceinline__ float allred_add16_s(float v) {
    asm volatile(
        "s_nop 1\n\t"
        "v_add_f32_dpp %0,%0,%0 row_ror:8 row_mask:0xf bank_mask:0xf\n\t"
        "s_nop 1\n\t"
        "v_add_f32_dpp %0,%0,%0 row_ror:4 row_mask:0xf bank_mask:0xf\n\t"
        "s_nop 1\n\t"
        "v_add_f32_dpp %0,%0,%0 row_ror:2 row_mask:0xf bank_mask:0xf\n\t"
        "s_nop 1\n\t"
        "v_add_f32_dpp %0,%0,%0 row_ror:1 row_mask:0xf bank_mask:0xf"
        : "+v"(v));
    return v;
}
__device__ __forceinline__ void allred_add16_x4(float& a, float& b, float& c, float& d) {
    asm volatile(
        "s_nop 1\n\t"
        "v_add_f32_dpp %0,%0,%0 row_ror:8 row_mask:0xf bank_mask:0xf\n\t"
        "v_add_f32_dpp %1,%1,%1 row_ror:8 row_mask:0xf bank_mask:0xf\n\t"
        "v_add_f32_dpp %2,%2,%2 row_ror:8 row_mask:0xf bank_mask:0xf\n\t"
        "v_add_f32_dpp %3,%3,%3 row_ror:8 row_mask:0xf bank_mask:0xf\n\t"
        "v_add_f32_dpp %0,%0,%0 row_ror:4 row_mask:0xf bank_mask:0xf\n\t"
        "v_add_f32_dpp %1,%1,%1 row_ror:4 row_mask:0xf bank_mask:0xf\n\t"
        "v_add_f32_dpp %2,%2,%2 row_ror:4 row_mask:0xf bank_mask:0xf\n\t"
        "v_add_f32_dpp %3,%3,%3 row_ror:4 row_mask:0xf bank_mask:0xf\n\t"
        "v_add_f32_dpp %0,%0,%0 row_ror:2 row_mask:0xf bank_mask:0xf\n\t"
        "v_add_f32_dpp %1,%1,%1 row_ror:2 row_mask:0xf bank_mask:0xf\n\t"
        "v_add_f32_dpp %2,%2,%2 row_ror:2 row_mask:0xf bank_mask:0xf\n\t"
        "v_add_f32_dpp %3,%3,%3 row_ror:2 row_mask:0xf bank_mask:0xf\n\t"
        "v_add_f32_dpp %0,%0,%0 row_ror:1 row_mask:0xf bank_mask:0xf\n\t"
        "v_add_f32_dpp %1,%1,%1 row_ror:1 row_mask:0xf bank_mask:0xf\n\t"
        "v_add_f32_dpp %2,%2,%2 row_ror:1 row_mask:0xf bank_mask:0xf\n\t"
        "v_add_f32_dpp %3,%3,%3 row_ror:1 row_mask:0xf bank_mask:0xf"
        : "+v"(a), "+v"(b), "+v"(c), "+v"(d));
}

__device__ __forceinline__ void wave_ds_fence() {
    asm volatile("s_waitcnt lgkmcnt(0)" ::: "memory");
}

template <int CODE>
__device__ __forceinline__ float swz_xor(float v) {
    return __int_as_float(__builtin_amdgcn_ds_swizzle(__float_as_int(v), CODE));
}

// bf16 U layout (R7/R16, measured 0 bank conflicts): short index
// = q*256 + ((((o>>2)^(q&15))<<2) | (o&3)); b64 writes/reads conflict-free.
__device__ __forceinline__ int sidx(int q, int o) {
    return q * 256 + ((((o >> 2) ^ (q & 15)) << 2) | (o & 3));
}
__device__ __forceinline__ float bf_lo(unsigned u) { return __uint_as_float(u << 16); }
__device__ __forceinline__ float bf_hi(unsigned u) { return __uint_as_float(u & 0xffff0000u); }

// One block per (b,t), 4 waves, zero barriers, 16 KB LDS -> 8 blocks/CU.
// Best verified configuration (R16, 32.6 us): MFMA conv (transposed, bias
// folded into Kp k-row 24), bf16 U tile for 8-block residency, wave-private
// LDS with lgkmcnt-only fences, single-inst DPP allreduces, no-max exp2
// softmax, ds_swizzle butterfly reduce-scatter epilogue.
__global__ __launch_bounds__(256, 8) void caps_kernel(
    const float* __restrict__ x,     // (B,T,32,8)
    const float* __restrict__ Bw,    // (T,16,1,32)
    const uint4* __restrict__ Kp,    // packed bf16 K fragments (+bias row)
    float* __restrict__ out)         // (B,T,16,16)
{
    const int bt  = blockIdx.x;
    const int t   = bt & (T_DIM - 1);
    const int tid = threadIdx.x;
    const int l   = tid & 63;
    const int w   = tid >> 6;
    const int kb  = l >> 4;
    const int r16 = l & 15;
    const int n   = tid >> 4, j = tid & 15;

    __shared__ unsigned short U16[32 * 256];   // swizzled bf16 U

    // ---- Bw prefetch ----
    const float bwj0 = Bw[(size_t)t * 512 + n * 32 + j];
    const float bwj1 = Bw[(size_t)t * 512 + n * 32 + 16 + j];

    // ---- B fragments: X^T columns (kt == kb); kb==3 = bias partner 1.0 ----
    short8 bx[2];
    if (kb == 3) {
        union { short8 s; uint4 u; } one;
        one.u = make_uint4(0x00003F80u, 0u, 0u, 0u);   // bf16(1.0) at e0
        bx[0] = bx[1] = one.s;
    } else {
        const int  tt    = t + kb - 1;
        const bool valid = (tt >= 0) && (tt < T_DIM);
        #pragma unroll
        for (int qt = 0; qt < 2; ++qt) {
            float4 x0 = make_float4(0.f, 0.f, 0.f, 0.f), x1 = x0;
            if (valid) {
                const float* xp = x + ((size_t)(bt + kb - 1) * 256 + (qt * 16 + r16) * 8);
                x0 = *reinterpret_cast<const float4*>(xp);
                x1 = *reinterpret_cast<const float4*>(xp + 4);
            }
            union { short8 s; uint4 u; } bu;
            bu.u.x = pk_bf16(x0.x, x0.y);
            bu.u.y = pk_bf16(x0.z, x0.w);
            bu.u.z = pk_bf16(x1.x, x1.y);
            bu.u.w = pk_bf16(x1.z, x1.w);
            bx[qt] = bu.s;
        }
    }

    // ---- A fragments from pre-packed Kp (coalesced b128, L1-hot) ----
    short8 af[4];
    #pragma unroll
    for (int oti = 0; oti < 4; ++oti) {
        union { short8 s; uint4 u; } au;
        au.u = Kp[kb * 256 + w * 64 + oti * 16 + r16];
        af[oti] = au.s;
    }

    // ---- conv MFMAs ----
    const f32x4 z = (f32x4){0.f, 0.f, 0.f, 0.f};
    f32x4 acc[2][4];
    #pragma unroll
    for (int qt = 0; qt < 2; ++qt)
        #pragma unroll
        for (int oti = 0; oti < 4; ++oti)
            acc[qt][oti] = __builtin_amdgcn_mfma_f32_16x16x32_bf16(
                af[oti], bx[qt], z, 0, 0, 0);

    // ---- epilogue: relu -> bf16 -> swizzled b64 writes ----
    #pragma unroll
    for (int qt = 0; qt < 2; ++qt) {
        const int q = qt * 16 + r16;
        #pragma unroll
        for (int oti = 0; oti < 4; ++oti) {
            const int obase = w * 64 + oti * 16 + kb * 4;
            uint2 pk;
            pk.x = pk_bf16(fmaxf(acc[qt][oti][0], 0.f), fmaxf(acc[qt][oti][1], 0.f));
            pk.y = pk_bf16(fmaxf(acc[qt][oti][2], 0.f), fmaxf(acc[qt][oti][3], 0.f));
            *reinterpret_cast<uint2*>(&U16[sidx(q, obase)]) = pk;
        }
    }

    wave_ds_fence();   // all phase-2 reads touch only this wave's columns

    // ---- phase 2: thread = (head n, lane j) ----
    f32x4 r0[4], r1[4];
    #pragma unroll
    for (int i = 0; i < 4; ++i) {
        const uint2 a = *reinterpret_cast<const uint2*>(&U16[sidx(j,      n * 16 + 4 * i)]);
        const uint2 c = *reinterpret_cast<const uint2*>(&U16[sidx(j + 16, n * 16 + 4 * i)]);
        r0[i] = (f32x4){bf_lo(a.x), bf_hi(a.x), bf_lo(a.y), bf_hi(a.y)};
        r1[i] = (f32x4){bf_lo(c.x), bf_hi(c.x), bf_lo(c.y), bf_hi(c.y)};
    }

    // V[d] = sum_q U[q][d] (DPP allreduce over 16 lanes)
    f32x4 V[4];
    #pragma unroll
    for (int i = 0; i < 4; ++i) {
        V[i] = r0[i] + r1[i];
        float a = V[i][0], b = V[i][1], c = V[i][2], d = V[i][3];
        allred_add16_x4(a, b, c, d);
        V[i] = (f32x4){a, b, c, d};
    }

    // scores (unscaled dots)
    float s0 = 0.f, s1 = 0.f;
    #pragma unroll
    for (int i = 0; i < 4; ++i)
        #pragma unroll
        for (int c = 0; c < 4; ++c) {
            s0 = fmaf(V[i][c], r0[i][c], s0);
            s1 = fmaf(V[i][c], r1[i][c], s1);
        }

    // softmax over 32 q: exp(s/sqrt8) = exp2(s*C2); no max-sub (data-bounded)
    const float C2 = 0.51011597846f;   // (1/sqrt(8)) * log2(e)
    const float e0 = exp2f(s0 * C2), e1 = exp2f(s1 * C2);
    const float es = allred_add16_s(e0 + e1);
    const float inv = __builtin_amdgcn_rcpf(es);
    const float c0 = fmaf(e0, inv, bwj0);
    const float c1 = fmaf(e1, inv, bwj1);

    // per-lane partials for all 16 output components
    float op16[16];
    #pragma unroll
    for (int i = 0; i < 4; ++i)
        #pragma unroll
        for (int c = 0; c < 4; ++c)
            op16[4 * i + c] = fmaf(c0, r0[i][c], c1 * r1[i][c]);

    // butterfly reduce-scatter over the 16-lane group: lane j -> out[j]
    float v8[8];
    #pragma unroll
    for (int s = 0; s < 8; ++s) {
        const float kp = (j & 8) ? op16[s + 8] : op16[s];
        const float sd = (j & 8) ? op16[s] : op16[s + 8];
        v8[s] = kp + swz_xor<0x201F>(sd);
    }
    float v4[4];
    #pragma unroll
    for (int s = 0; s < 4; ++s) {
        const float kp = (j & 4) ? v8[s + 4] : v8[s];
        const float sd = (j & 4) ? v8[s] : v8[s + 4];
        v4[s] = kp + swz_xor<0x101F>(sd);
    }
    float v2[2];
    #pragma unroll
    for (int s = 0; s < 2; ++s) {
        const float kp = (j & 2) ? v4[s + 2] : v4[s];
        const float sd = (j & 2) ? v4[s] : v4[s + 2];
        v2[s] = kp + swz_xor<0x081F>(sd);
    }
    const float kp1 = (j & 1) ? v2[1] : v2[0];
    const float sd1 = (j & 1) ? v2[0] : v2[1];
    const float ox = kp1 + swz_xor<0x041F>(sd1);

    // norm gate: ss = sum_d out[d]^2 via scalar allreduce
    const float ss  = allred_add16_s(ox * ox);
    const float nrm = sqrtf(ss);
    const float res = ss * __builtin_amdgcn_rcpf(ss + 1.f) *
                      (ox * __builtin_amdgcn_rcpf(nrm + 1e-7f));

    out[(size_t)bt * 256 + tid] = res;
}

extern "C" void kernel_launch(void* const* d_in, const int* in_sizes, int n_in,
                              void* d_out, int out_size, void* d_ws, size_t ws_size,
                              hipStream_t stream) {
    const float* x    = (const float*)d_in[0];
    const float* K    = (const float*)d_in[1];
    const float* bias = (const float*)d_in[2];
    const float* Bw   = (const float*)d_in[3];
    float* out        = (float*)d_out;
    uint4* Kp         = (uint4*)d_ws;            // 16 KB scratch

    kpack_kernel<<<4, 256, 0, stream>>>(K, bias, Kp);

    const int B  = in_sizes[0] / (T_DIM * 32 * 8);   // = 8
    const int nb = B * T_DIM;                        // 8192 blocks
    caps_kernel<<<nb, 256, 0, stream>>>(x, Bw, Kp, out);
}